// Round 14
// baseline (721.798 us; speedup 1.0000x reference)
//
#include <hip/hip_runtime.h>
#include <math.h>

#define HW 245760          // 384*640
#define H_IN 384
#define W_IN 640

// ---- workspace layout (float offsets) ----
#define X1_OFF   0UL          // fp32 planar x1: fallback only
#define C1_OFF   31457280UL   // 2*32*190*318 = 3866880
#define C2_OFF   35324160UL   // 2*32*95*159 = 966720
#define C3_OFF   36290880UL   // (unused in MFMA path)
#define T1_OFF   36536640UL   // 128
#define REP_OFF  36536768UL   // 4096
#define GX_OFF   36540864UL   // 32768 (lstm gx; later conv3b partial sums)
#define WSF_OFF  36573632UL
#define WSB_OFF  36598208UL
#define OW_OFF   36622784UL
#define CO_OFF   36647360UL
#define PAR_OFF  36647424UL
#define FP_OFF   36664192UL
// PAR sub-offsets
#define P_W1T 0
#define P_W2T 8192
#define P_B1  16384
#define P_B2  16448
#define P_SC  16512
#define P_SH  16640

// ---- bf16 region (byte offsets) ----
// xbf layout: [plane p=c>>4][b][px][16ch] bf16
#define X1BF_BYTES_OFF 146656800UL
#define X1BF_BYTES     62914560UL
#define WBF_BYTES_OFF  (X1BF_BYTES_OFF + X1BF_BYTES)
#define WBF_BYTES      802816UL
#define REQ_BYTES      (WBF_BYTES_OFF + WBF_BYTES)

typedef short short8 __attribute__((ext_vector_type(8)));
typedef unsigned short ushort8_t __attribute__((ext_vector_type(8)));
typedef float f32x16 __attribute__((ext_vector_type(16)));

__device__ __forceinline__ float sigf(float x){ return 1.f/(1.f+expf(-x)); }

__device__ __forceinline__ unsigned short f2bf(float f){
  union { float f; unsigned u; } x; x.f = f;
  unsigned r = x.u + 0x7fffu + ((x.u >> 16) & 1u);   // RNE
  return (unsigned short)(r >> 16);
}
__device__ __forceinline__ float bf2f(unsigned short u){
  union { unsigned u; float f; } x; x.u = ((unsigned)u) << 16; return x.f;
}

// ---------------- rep stage 1 ----------------------------------------------
__global__ __launch_bounds__(256) void k_rep1(const float* __restrict__ cond,
                                              const float* __restrict__ w1,
                                              float* __restrict__ ws){
  const int gid = blockIdx.x*256 + threadIdx.x;
  const int o = gid >> 6;
  const int lane = gid & 63;
  const int r = o >> 6, oc = o & 63;
  const float4* c4 = (const float4*)(cond + r*7680);
  const float4* w4 = (const float4*)(w1 + oc*7680);
  float s = 0.f;
  #pragma unroll 6
  for (int i = lane; i < 1920; i += 64){
    float4 a = c4[i], b = w4[i];
    s += a.x*b.x + a.y*b.y + a.z*b.z + a.w*b.w;
  }
  #pragma unroll
  for (int off = 32; off; off >>= 1) s += __shfl_xor(s, off, 64);
  if (lane == 0) ws[T1_OFF + o] = s > 0.f ? s : 0.1f*s;
}

// ---------------- rep stage 2 -----------------------------------------------
__global__ __launch_bounds__(256) void k_rep2(const float* __restrict__ w2,
                                              float* __restrict__ ws){
  int gid = blockIdx.x*256 + threadIdx.x;
  int r = gid >> 11, j = gid & 2047;
  const float* t1 = ws + T1_OFF + r*64;
  const float* wr = w2 + j*64;
  float s = 0.f;
  #pragma unroll
  for (int k=0;k<64;k++) s += t1[k]*wr[k];
  ws[REP_OFF + gid] = s;
}

// ---------------- gx --------------------------------------------------------
__global__ __launch_bounds__(256) void k_gx(const float* __restrict__ wfw,
                                            const float* __restrict__ wbw,
                                            float* __restrict__ ws){
  int gid = blockIdx.x*256 + threadIdx.x;
  int dir = gid >> 14; int rem = gid & 16383;
  int r = rem >> 8; int m = rem & 255;
  const float* w = (dir ? wbw : wfw) + m*128;
  const float* rp = ws + REP_OFF + r*64;
  float s = 0.f;
  #pragma unroll
  for (int k=0;k<64;k++) s += rp[k]*w[k];
  ws[GX_OFF + gid] = s;
}

// ---------------- LSTM ------------------------------------------------------
__global__ __launch_bounds__(256) void k_lstm(const float* __restrict__ wfw,
                                              const float* __restrict__ wbw,
                                              float* __restrict__ ws){
  const int rg = blockIdx.x, dir = blockIdx.y;
  const int tid = threadIdx.x;
  const int gi = tid >> 6, col = tid & 63;
  const float* w = dir ? wbw : wfw;
  const float* gx = ws + GX_OFF + (size_t)dir*16384;
  float* outp = ws + (dir ? WSB_OFF : WSF_OFF);
  float wr[64];
  const float4* wrow = (const float4*)(w + (gi*64+col)*128 + 64);
  #pragma unroll
  for (int k4=0;k4<16;k4++){
    float4 t = wrow[k4];
    wr[k4*4+0]=t.x; wr[k4*4+1]=t.y; wr[k4*4+2]=t.z; wr[k4*4+3]=t.w;
  }
  __shared__ __align__(16) float hl[512];
  __shared__ float gl[2048];
  hl[tid] = 0.f; hl[tid+256] = 0.f;
  float cs0 = 0.f, cs1 = 0.f;
  __syncthreads();
  for (int t=0;t<6;t++){
    float acc[8];
    #pragma unroll
    for (int r=0;r<8;r++) acc[r] = gx[(rg*8+r)*256 + gi*64 + col];
    #pragma unroll
    for (int r=0;r<8;r++){
      #pragma unroll
      for (int k4=0;k4<16;k4++){
        float4 h4 = *(const float4*)&hl[r*64 + k4*4];
        acc[r] += h4.x*wr[k4*4] + h4.y*wr[k4*4+1] + h4.z*wr[k4*4+2] + h4.w*wr[k4*4+3];
      }
    }
    #pragma unroll
    for (int r=0;r<8;r++) gl[r*256 + gi*64 + col] = acc[r];
    __syncthreads();
    {
      int r = tid >> 6, cc = tid & 63;
      float vi = gl[r*256+cc], vf = gl[r*256+64+cc], vo = gl[r*256+128+cc], vg = gl[r*256+192+cc];
      cs0 = sigf(vf)*cs0 + sigf(vi)*tanhf(vg);
      float h = sigf(vo)*tanhf(cs0);
      hl[r*64+cc] = h;
      outp[t*4096 + (rg*8+r)*64 + cc] = h;
    }
    {
      int cid = tid + 256; int r = cid >> 6, cc = cid & 63;
      float vi = gl[r*256+cc], vf = gl[r*256+64+cc], vo = gl[r*256+128+cc], vg = gl[r*256+192+cc];
      cs1 = sigf(vf)*cs1 + sigf(vi)*tanhf(vg);
      float h = sigf(vo)*tanhf(cs1);
      hl[r*64+cc] = h;
      outp[t*4096 + (rg*8+r)*64 + cc] = h;
    }
    __syncthreads();
  }
}

// ---------------- ow --------------------------------------------------------
__global__ __launch_bounds__(256) void k_ow(const float* __restrict__ lcw,
                                            const float* __restrict__ lcb,
                                            float* __restrict__ ws){
  int gid = blockIdx.x*256 + threadIdx.x;
  int t = gid >> 12; int rem = gid & 4095;
  int r = rem >> 6; int cc = rem & 63;
  const float* wf = lcw + t*8192 + cc*128;
  const float* xf = ws + WSF_OFF + t*4096 + r*64;
  const float* xb = ws + WSB_OFF + (size_t)(5-t)*4096 + r*64;
  float s = lcb[t*64+cc];
  #pragma unroll
  for (int k=0;k<64;k++) s += xf[k]*wf[k];
  #pragma unroll
  for (int k=0;k<64;k++) s += xb[k]*wf[64+k];
  ws[OW_OFF + gid] = s;
}

// ---------------- x1 = conv_first (1x1, 3->64) + bias -----------------------
__global__ __launch_bounds__(256) void k_convfirst(const float* __restrict__ x,
                                                   const float* __restrict__ cw,
                                                   const float* __restrict__ cb,
                                                   float* __restrict__ x1planar,
                                                   unsigned short* __restrict__ xbf){
  __shared__ float wsm[192];
  __shared__ float bsm[64];
  const int tid = threadIdx.x, blk = blockIdx.x;
  const int b = blk / 960;
  const int px = (blk % 960)*256 + tid;
  if (tid < 192) wsm[tid] = cw[tid];
  if (tid < 64)  bsm[tid] = cb[tid];
  __syncthreads();
  float x0 = x[(size_t)(b*3+0)*HW + px];
  float x1v = x[(size_t)(b*3+1)*HW + px];
  float x2 = x[(size_t)(b*3+2)*HW + px];
  float* o = x1planar ? (x1planar + (size_t)b*64*HW + px) : (float*)0;
  #pragma unroll
  for (int i=0;i<8;i++){
    ushort8_t u;
    #pragma unroll
    for (int j=0;j<8;j++){
      int oc = i*8+j;
      float v = bsm[oc] + wsm[oc*3]*x0 + wsm[oc*3+1]*x1v + wsm[oc*3+2]*x2;
      if (x1planar) o[(size_t)oc*HW] = v;
      u[j] = f2bf(v);
    }
    if (xbf)
      *(ushort8_t*)(xbf + (((size_t)(i>>1)*2 + b)*HW + px)*16 + (i&1)*8) = u;
  }
}

// ---------------- weight repack ---------------------------------------------
__global__ __launch_bounds__(256) void k_wbf(const float* __restrict__ bc1w,
                                             const float* __restrict__ fc1w,
                                             unsigned short* __restrict__ wbf){
  int e = blockIdx.x*256 + threadIdx.x;
  int s = e / 100352; int r = e - s*100352;
  int tap = r >> 11; int rem = r & 2047; int oc = rem >> 6; int ic = rem & 63;
  const float* src = (s < 3) ? (bc1w + (size_t)s*100352) : fc1w;
  wbf[e] = f2bf(src[((size_t)oc*64 + ic)*49 + tap]);
}

// ---------------- MFMA 7x7 s2 conv (v7: A direct from global/L2) ------------
// 256 thr = 4 waves x 2 rows, 8-row tile, grid (10,24,2)=480 blocks.
// No input LDS: A-frags are predicated global loads (L1/L2-cached, ~7x reuse
// per block). LDS holds only the per-kc weight tile (50KB) -> 3 blocks/CU.
__global__ __launch_bounds__(256) void k_conv7_mfma(
    const unsigned short* __restrict__ xbf,   // [4][2][HW][16] bf16 planes
    const unsigned short* __restrict__ wbf,   // [49][32][64] one set
    const float* __restrict__ bias,
    float* __restrict__ out)                  // [b][32][190][318]
{
  __shared__ __align__(16) unsigned short wS[49*32*16];     // 50176 B
  const int tid = threadIdx.x;
  const int wv = tid >> 6, l = tid & 63;
  const int mrow = l & 31, khalf = l >> 5;
  const int wo0 = blockIdx.x * 32, ho0 = blockIdx.y * 8;
  const int b = blockIdx.z;
  const int r0 = 2*ho0 - 1;

  f32x16 acc0, acc1;
  #pragma unroll
  for (int i=0;i<16;i++){ acc0[i]=0.f; acc1[i]=0.f; }

  const short8 zero8 = {0,0,0,0,0,0,0,0};

  for (int kc = 0; kc < 4; ++kc){
    const unsigned short* xplane = xbf + ((size_t)(kc*2 + b))*HW*16;
    __syncthreads();
    for (int idx = tid; idx < 49*32*2; idx += 256){
      int half = idx & 1; int e = idx >> 1;    // e = tap*32+oc
      uint4 v = *(const uint4*)(wbf + ((size_t)e*64 + kc*16 + half*8));
      *(uint4*)(wS + ((size_t)e*16 + half*8)) = v;
    }
    __syncthreads();

    #pragma unroll
    for (int kw = 0; kw < 7; ++kw){
      const int p = (kw+1)&1;
      const int qoff = (kw - 1 - p)/2 + 1;
      const int col = 2*(qoff + mrow + wo0 - 1) + p;    // per-lane column
      const bool cok = (unsigned)col < 640u;
      const unsigned short* cbase = xplane + (size_t)col*16 + khalf*8;
      short8 A_[9];
      #define LDA(rr) { int r = r0 + 4*wv + (rr); \
        A_[rr] = zero8; \
        if (cok && (unsigned)r < 384u) A_[rr] = *(const short8*)(cbase + (size_t)r*640*16); }
      #define LDB(KH) (*(const short8*)(wS + ((((KH)*7+kw)*32 + mrow)*16 + khalf*8)))
      #define MF(AV,BV,AC) AC = __builtin_amdgcn_mfma_f32_32x32x16_bf16(AV, BV, AC, 0, 0, 0)
      LDA(0) LDA(1) LDA(2) LDA(3) LDA(4) LDA(5) LDA(6) LDA(7) LDA(8)
      #pragma unroll
      for (int kh = 0; kh < 7; ++kh){
        short8 Bq = LDB(kh);
        MF(A_[kh],   Bq, acc0);
        MF(A_[kh+2], Bq, acc1);
      }
      #undef LDA
      #undef LDB
      #undef MF
    }
  }

  const float bv = bias[mrow];
  #pragma unroll
  for (int mt = 0; mt < 2; ++mt){
    int ho = ho0 + 2*wv + mt;
    if (ho >= 190) continue;
    f32x16 av = mt ? acc1 : acc0;
    float* orow = out + (((size_t)b*32 + mrow)*190 + ho)*318;
    #pragma unroll
    for (int r = 0; r < 16; ++r){
      int m = (r&3) + 8*(r>>2) + 4*khalf;
      int wo = wo0 + m;
      if (wo < 318) orow[wo] = fmaxf(av[r] + bv, 0.f);
    }
  }
}

// ---------------- fp32 fallback 7x7 conv ------------------------------------
__global__ __launch_bounds__(256) void k_conv7(const float* __restrict__ in,
                                               const float* __restrict__ w,
                                               const float* __restrict__ bias,
                                               float* __restrict__ out){
  __shared__ float patch[37*37];
  __shared__ __align__(16) float wl[49*32];
  const int tid = threadIdx.x;
  const int og = tid >> 5, s = tid & 31;
  const int sy = s >> 1, sx0 = (s & 1)*8;
  const int bx = blockIdx.x, by = blockIdx.y, b = blockIdx.z;
  const int ir0 = by*32 - 1, ic0 = bx*32 - 1;
  float acc[4][8];
  #pragma unroll
  for (int i=0;i<4;i++)
    #pragma unroll
    for (int k=0;k<8;k++) acc[i][k]=0.f;
  for (int c=0;c<64;c++){
    const float* src = in + (size_t)(b*64+c)*HW;
    for (int idx=tid; idx<1369; idx+=256){
      int r = idx/37; int cc = idx - r*37;
      int ir = ir0 + r, ic = ic0 + cc;
      float v = 0.f;
      if ((unsigned)ir < H_IN && (unsigned)ic < W_IN) v = src[ir*W_IN + ic];
      patch[idx] = v;
    }
    for (int idx=tid; idx<1568; idx+=256)
      wl[idx] = w[((size_t)(idx&31)*64 + c)*49 + (idx>>5)];
    __syncthreads();
    #pragma unroll
    for (int kh=0;kh<7;kh++){
      const float* prow = &patch[(2*sy+kh)*37 + 2*sx0];
      #pragma unroll
      for (int kw=0;kw<7;kw++){
        float4 wv = *(const float4*)&wl[(kh*7+kw)*32 + og*4];
        #pragma unroll
        for (int i=0;i<8;i++){
          float xv = prow[2*i + kw];
          acc[0][i] += wv.x*xv; acc[1][i] += wv.y*xv;
          acc[2][i] += wv.z*xv; acc[3][i] += wv.w*xv;
        }
      }
    }
    __syncthreads();
  }
  const int ho = by*16 + sy;
  if (ho < 190){
    #pragma unroll
    for (int oo=0;oo<4;oo++){
      int o = og*4+oo; float bb = bias[o];
      float* orow = out + ((size_t)(b*32+o)*190 + ho)*318 + bx*16 + sx0;
      #pragma unroll
      for (int i=0;i<8;i++){
        int wo = bx*16 + sx0 + i;
        if (wo < 318) orow[i] = fmaxf(acc[oo][i] + bb, 0.f);
      }
    }
  }
}

// ---------------- 3x3 s2 p1 conv + optional fused spatial-sum ---------------
__global__ __launch_bounds__(256) void k_conv3_fast(const float* __restrict__ in,
                                                    const float* __restrict__ w,
                                                    const float* __restrict__ bias,
                                                    float* __restrict__ out,
                                                    int Hi, int Wi, int Ho, int Wo,
                                                    float* __restrict__ co_partial){
  __shared__ __align__(16) float wl[32*9*8];   // [ic][k][8oc]
  __shared__ float wsum[4][4];
  const int tid = threadIdx.x;
  const int b = blockIdx.z;
  const int oc0 = blockIdx.y * 8;
  for (int idx = tid; idx < 2304; idx += 256){
    int ol = idx & 7; int rest = idx >> 3;
    int ic = rest / 9, k = rest - ic*9;
    wl[idx] = w[((size_t)(oc0+ol)*32 + ic)*9 + k];
  }
  __syncthreads();
  const int pxl = tid & 127, ocg = tid >> 7;
  const int HoWo = Ho*Wo;
  const int opx = blockIdx.x*128 + pxl;
  float acc0=0.f, acc1=0.f, acc2=0.f, acc3=0.f;
  if (opx < HoWo){
    const int ho = opx / Wo, wo = opx - ho*Wo;
    const int ir0 = 2*ho - 1, ic0 = 2*wo - 1;
    const float* inb = in + (size_t)b*32*Hi*Wi;
    for (int c = 0; c < 32; ++c){
      const float* src = inb + (size_t)c*Hi*Wi;
      float xv[9];
      #pragma unroll
      for (int kh=0;kh<3;kh++){
        int ir = ir0 + kh;
        bool rok = (unsigned)ir < (unsigned)Hi;
        #pragma unroll
        for (int kw=0;kw<3;kw++){
          int icc = ic0 + kw;
          xv[kh*3+kw] = (rok && (unsigned)icc < (unsigned)Wi) ? src[ir*Wi + icc] : 0.f;
        }
      }
      const float* wc = &wl[c*72 + ocg*4];
      #pragma unroll
      for (int k=0;k<9;k++){
        float4 wa = *(const float4*)(wc + k*8);
        float x = xv[k];
        acc0 += wa.x*x; acc1 += wa.y*x; acc2 += wa.z*x; acc3 += wa.w*x;
      }
    }
    acc0 = fmaxf(acc0 + bias[oc0+ocg*4+0], 0.f);
    acc1 = fmaxf(acc1 + bias[oc0+ocg*4+1], 0.f);
    acc2 = fmaxf(acc2 + bias[oc0+ocg*4+2], 0.f);
    acc3 = fmaxf(acc3 + bias[oc0+ocg*4+3], 0.f);
    if (!co_partial){
      float* ob = out + ((size_t)(b*32 + oc0 + ocg*4))*HoWo + opx;
      ob[0] = acc0;
      ob[(size_t)HoWo] = acc1;
      ob[(size_t)2*HoWo] = acc2;
      ob[(size_t)3*HoWo] = acc3;
    }
  }
  if (co_partial){
    float r0=acc0, r1=acc1, r2=acc2, r3=acc3;
    #pragma unroll
    for (int off=32; off; off>>=1){
      r0 += __shfl_xor(r0, off, 64);
      r1 += __shfl_xor(r1, off, 64);
      r2 += __shfl_xor(r2, off, 64);
      r3 += __shfl_xor(r3, off, 64);
    }
    int wvid = tid >> 6;
    if ((tid & 63) == 0){
      wsum[wvid][0]=r0; wsum[wvid][1]=r1; wsum[wvid][2]=r2; wsum[wvid][3]=r3;
    }
    __syncthreads();
    if (tid < 8){
      int i = tid & 3; int pair = tid >> 2;
      float v = wsum[pair*2][i] + wsum[pair*2+1][i];
      co_partial[(size_t)blockIdx.x*64 + b*32 + oc0 + pair*4 + i] = v;
    }
  }
}

// ---------------- per-block params (parallelized) ---------------------------
__global__ __launch_bounds__(256) void k_mkparams(const float* __restrict__ bsw, const float* __restrict__ bsb,
                                                  const float* __restrict__ bhw, const float* __restrict__ bhb,
                                                  const float* __restrict__ dyn1, const float* __restrict__ sh1w, const float* __restrict__ sh1b,
                                                  const float* __restrict__ dyn2, const float* __restrict__ sh2w, const float* __restrict__ sh2b,
                                                  int j2, float* __restrict__ ws,
                                                  unsigned short* __restrict__ w1oc,
                                                  unsigned short* __restrict__ w2oc){
  const int bid = blockIdx.x;
  const int tid = threadIdx.x;
  float* P = ws + PAR_OFF;
  if (bid < 16){
    const float* ow1 = ws + OW_OFF + (size_t)j2*4096;
    const float* ow2 = ws + OW_OFF + (size_t)(j2+1)*4096;
    for (int idx = bid*256 + tid; idx < 8192; idx += 4096){
      int b = idx>>12, rem = idx&4095, c = rem>>6, o = rem&63;
      float v1, v2;
      if (o < 32){
        v1 = dyn1[o*64+c]*ow1[(b*32+o)*64+c];
        v2 = dyn2[o*64+c]*ow2[(b*32+o)*64+c];
      } else {
        v1 = sh1w[(o-32)*64+c];
        v2 = sh2w[(o-32)*64+c];
      }
      P[P_W1T + idx] = v1;
      P[P_W2T + idx] = v2;
      int t = b*4096 + o*64 + c;
      w1oc[t] = f2bf(v1);
      w2oc[t] = f2bf(v2);
    }
  } else {
    __shared__ float coL[64];
    const float* part = ws + GX_OFF;
    if (tid < 64){
      float s = 0.f;
      for (int bx=0;bx<30;bx++) s += part[bx*64 + tid];
      coL[tid] = s * (1.f/3840.f);
    }
    __syncthreads();
    if (tid < 128){
      int b = tid>>6, o = tid&63;
      float s = bsb[o];
      #pragma unroll
      for (int k=0;k<32;k++) s += coL[b*32+k]*bsw[o*32+k];
      P[P_SC + tid] = 1.f + s;
    } else {
      int t2 = tid-128; int b = t2>>6, o = t2&63;
      float s = bhb[o];
      #pragma unroll
      for (int k=0;k<32;k++) s += coL[b*32+k]*bhw[o*32+k];
      P[P_SH + t2] = s;
    }
    if (tid < 64){
      P[P_B1+tid] = (tid<32) ? 0.f : sh1b[tid-32];
      P[P_B2+tid] = (tid<32) ? 0.f : sh2b[tid-32];
    }
  }
}

// ---------------- MFMA fused dynamic block (bf16-resident x1, planes) -------
__global__ __launch_bounds__(256, 4) void k_pointwise_mfma(
    const float* __restrict__ ws,
    const unsigned short* __restrict__ w1oc,
    const unsigned short* __restrict__ w2oc,
    unsigned short* __restrict__ xbf)
{
  __shared__ float scs[64], shs[64], b1s[64], b2s[64];
  __shared__ __align__(16) uint4 outbuf[2048];
  const int tid = threadIdx.x;
  const int blk = blockIdx.x;
  const int b = blk / 960;
  const int px0 = (blk % 960) * 256;
  const float* P = ws + PAR_OFF;
  if (tid < 64){
    scs[tid] = P[P_SC + b*64 + tid];
    shs[tid] = P[P_SH + b*64 + tid];
    b1s[tid] = P[P_B1 + tid];
    b2s[tid] = P[P_B2 + tid];
  }
  __syncthreads();
  const int wv = tid >> 6, l = tid & 63;
  const int lane31 = l & 31, myh = l >> 5;
  const unsigned short* w1g = w1oc + (size_t)b*4096;
  const unsigned short* w2g = w2oc + (size_t)b*4096;

  #pragma unroll
  for (int nt = 0; nt < 2; ++nt){
    const int pxl = wv*64 + nt*32 + lane31;
    const int mypx = px0 + pxl;
    short8 Bsave[4];
    f32x16 a1_0, a1_1;
    #pragma unroll
    for (int i=0;i<16;i++){ a1_0[i]=0.f; a1_1[i]=0.f; }
    #pragma unroll
    for (int kc=0;kc<4;kc++){
      short8 Bx = *(const short8*)(xbf + ((size_t)(kc*2+b)*HW + mypx)*16 + myh*8);
      Bsave[kc] = Bx;
      short8 A0 = *(const short8*)(w1g + (size_t)lane31*64 + kc*16 + myh*8);
      short8 A1 = *(const short8*)(w1g + (size_t)(32+lane31)*64 + kc*16 + myh*8);
      a1_0 = __builtin_amdgcn_mfma_f32_32x32x16_bf16(A0, Bx, a1_0, 0, 0, 0);
      a1_1 = __builtin_amdgcn_mfma_f32_32x32x16_bf16(A1, Bx, a1_1, 0, 0, 0);
    }
    unsigned hp0[8], hp1[8];
    #pragma unroll
    for (int mt=0;mt<2;mt++){
      #pragma unroll
      for (int p=0;p<8;p++){
        unsigned half0=0, half1=0;
        #pragma unroll
        for (int e=0;e<2;e++){
          int reg = 2*p+e;
          int o1 = mt*32 + (reg&3) + 8*(reg>>2) + 4*myh;
          float v = mt ? a1_1[reg] : a1_0[reg];
          float t = (v + b1s[o1]) * scs[o1] + shs[o1];
          t = fmaxf(t, 0.f);
          if (e) half1 = f2bf(t); else half0 = f2bf(t);
        }
        unsigned pk = half0 | (half1<<16);
        if (mt) hp1[p] = pk; else hp0[p] = pk;
      }
    }
    f32x16 a2_0, a2_1;
    #pragma unroll
    for (int i=0;i<16;i++){ a2_0[i]=0.f; a2_1[i]=0.f; }
    #pragma unroll
    for (int kc=0;kc<4;kc++){
      const int base = 4*(kc&1);
      unsigned e0,e1,e2,e3;
      if (kc < 2){ e0=hp0[base+0]; e1=hp0[base+1]; e2=hp0[base+2]; e3=hp0[base+3]; }
      else       { e0=hp1[base+0]; e1=hp1[base+1]; e2=hp1[base+2]; e3=hp1[base+3]; }
      unsigned sA = myh ? e0 : e2;
      unsigned sB = myh ? e1 : e3;
      unsigned rA = __shfl_xor(sA, 32, 64);
      unsigned rB = __shfl_xor(sB, 32, 64);
      union { unsigned u[4]; short8 s; } Bh;
      Bh.u[0] = myh ? rA : e0;
      Bh.u[1] = myh ? rB : e1;
      Bh.u[2] = myh ? e2 : rA;
      Bh.u[3] = myh ? e3 : rB;
      short8 A0 = *(const short8*)(w2g + (size_t)lane31*64 + kc*16 + myh*8);
      short8 A1 = *(const short8*)(w2g + (size_t)(32+lane31)*64 + kc*16 + myh*8);
      a2_0 = __builtin_amdgcn_mfma_f32_32x32x16_bf16(A0, Bh.s, a2_0, 0, 0, 0);
      a2_1 = __builtin_amdgcn_mfma_f32_32x32x16_bf16(A1, Bh.s, a2_1, 0, 0, 0);
    }
    #pragma unroll
    for (int mt2=0;mt2<2;mt2++){
      #pragma unroll
      for (int q=0;q<4;q++){
        float d[4], p[4];
        #pragma unroll
        for (int e=0;e<4;e++){
          int reg = 4*q+e;
          int ch = mt2*32 + e + 8*q + 4*myh;
          d[e] = (mt2 ? a2_1[reg] : a2_0[reg]) + b2s[ch];
        }
        #pragma unroll
        for (int e=0;e<4;e++) p[e] = __shfl_xor(d[e], 32, 64);
        if (myh == (q & 1)){
          float row8[8];
          #pragma unroll
          for (int e=0;e<4;e++){
            row8[e]   = myh ? p[e] : d[e];
            row8[4+e] = myh ? d[e] : p[e];
          }
          union { short8 s; unsigned short us[8]; } oldv;
          oldv.s = Bsave[2*mt2 + (q>>1)];
          unsigned w[4];
          #pragma unroll
          for (int k=0;k<4;k++){
            float n0 = bf2f(oldv.us[2*k+0]) + row8[2*k+0];
            float n1 = bf2f(oldv.us[2*k+1]) + row8[2*k+1];
            w[k] = (unsigned)f2bf(n0) | ((unsigned)f2bf(n1) << 16);
          }
          int slot = mt2*4 + q;
          outbuf[pxl*8 + ((slot + pxl) & 7)] = make_uint4(w[0],w[1],w[2],w[3]);
        }
      }
    }
  }
  __syncthreads();
  uint4* gout = (uint4*)xbf;
  #pragma unroll
  for (int k=0;k<8;k++){
    int idx = tid + k*256;
    int plane = idx >> 9, rem = idx & 511;
    int pxl = rem >> 1, half = rem & 1;
    int slot = plane*2 + half;
    gout[((size_t)(plane*2+b)*HW + px0 + pxl)*2 + half] = outbuf[pxl*8 + ((slot + pxl) & 7)];
  }
}

// ---------------- fallback fused dynamic block (fp32 VALU) ------------------
#define FMA4(A,W,X) { A.x += (W)*(X).x; A.y += (W)*(X).y; A.z += (W)*(X).z; A.w += (W)*(X).w; }
__global__ __launch_bounds__(128) void k_pointwise(float* __restrict__ ws){
  __shared__ __align__(16) float xt[64*128];
  __shared__ __align__(16) float wt[64*64];
  __shared__ float b1s[64], b2s[64], scs[64], shs[64];
  const int tid = threadIdx.x;
  const int blk = blockIdx.x;
  const int b = blk / 1920;
  const int px0 = (blk % 1920) * 128;
  float* x1 = ws + X1_OFF;
  const float* P = ws + PAR_OFF;
  const float4* xg = (const float4*)(x1 + (size_t)b*64*HW + px0);
  float4* xt4 = (float4*)xt;
  float4* wt4 = (float4*)wt;
  for (int idx=tid; idx<2048; idx+=128){
    int c = idx>>5, p4 = idx&31;
    xt4[c*32 + (p4&3)*8 + (p4>>2)] = xg[(size_t)c*(HW/4) + p4];
  }
  const float4* w1g = (const float4*)(P + P_W1T + b*4096);
  for (int idx=tid; idx<1024; idx+=128) wt4[idx] = w1g[idx];
  if (tid < 64){
    b1s[tid]=P[P_B1+tid]; b2s[tid]=P[P_B2+tid];
    scs[tid]=P[P_SC + b*64 + tid]; shs[tid]=P[P_SH + b*64 + tid];
  }
  __syncthreads();
  const int og = tid>>3, pg = tid&7, o0 = og*4;
  float4 a[4][4];
  #pragma unroll
  for (int oo=0;oo<4;oo++){
    float bv = b1s[o0+oo];
    a[oo][0]=a[oo][1]=a[oo][2]=a[oo][3]=make_float4(bv,bv,bv,bv);
  }
  for (int c=0;c<64;c++){
    float4 wv = wt4[c*16 + og];
    float4 x0 = xt4[c*32 + pg];
    float4 x1q = xt4[c*32 + 8 + pg];
    float4 x2 = xt4[c*32 + 16 + pg];
    float4 x3 = xt4[c*32 + 24 + pg];
    FMA4(a[0][0],wv.x,x0); FMA4(a[0][1],wv.x,x1q); FMA4(a[0][2],wv.x,x2); FMA4(a[0][3],wv.x,x3);
    FMA4(a[1][0],wv.y,x0); FMA4(a[1][1],wv.y,x1q); FMA4(a[1][2],wv.y,x2); FMA4(a[1][3],wv.y,x3);
    FMA4(a[2][0],wv.z,x0); FMA4(a[2][1],wv.z,x1q); FMA4(a[2][2],wv.z,x2); FMA4(a[2][3],wv.z,x3);
    FMA4(a[3][0],wv.w,x0); FMA4(a[3][1],wv.w,x1q); FMA4(a[3][2],wv.w,x2); FMA4(a[3][3],wv.w,x3);
  }
  #pragma unroll
  for (int oo=0;oo<4;oo++){
    float sc = scs[o0+oo], sh = shs[o0+oo];
    #pragma unroll
    for (int q=0;q<4;q++){
      a[oo][q].x = fmaxf(a[oo][q].x*sc + sh, 0.f);
      a[oo][q].y = fmaxf(a[oo][q].y*sc + sh, 0.f);
      a[oo][q].z = fmaxf(a[oo][q].z*sc + sh, 0.f);
      a[oo][q].w = fmaxf(a[oo][q].w*sc + sh, 0.f);
    }
  }
  __syncthreads();
  #pragma unroll
  for (int oo=0;oo<4;oo++)
    #pragma unroll
    for (int q=0;q<4;q++)
      xt4[(o0+oo)*32 + q*8 + pg] = a[oo][q];
  const float4* w2g = (const float4*)(P + P_W2T + b*4096);
  for (int idx=tid; idx<1024; idx+=128) wt4[idx] = w2g[idx];
  __syncthreads();
  #pragma unroll
  for (int oo=0;oo<4;oo++){
    float bv = b2s[o0+oo];
    a[oo][0]=a[oo][1]=a[oo][2]=a[oo][3]=make_float4(bv,bv,bv,bv);
  }
  for (int c=0;c<64;c++){
    float4 wv = wt4[c*16 + og];
    float4 x0 = xt4[c*32 + pg];
    float4 x1q = xt4[c*32 + 8 + pg];
    float4 x2 = xt4[c*32 + 16 + pg];
    float4 x3 = xt4[c*32 + 24 + pg];
    FMA4(a[0][0],wv.x,x0); FMA4(a[0][1],wv.x,x1q); FMA4(a[0][2],wv.x,x2); FMA4(a[0][3],wv.x,x3);
    FMA4(a[1][0],wv.y,x0); FMA4(a[1][1],wv.y,x1q); FMA4(a[1][2],wv.y,x2); FMA4(a[1][3],wv.y,x3);
    FMA4(a[2][0],wv.z,x0); FMA4(a[2][1],wv.z,x1q); FMA4(a[2][2],wv.z,x2); FMA4(a[2][3],wv.z,x3);
    FMA4(a[3][0],wv.w,x0); FMA4(a[3][1],wv.w,x1q); FMA4(a[3][2],wv.w,x2); FMA4(a[3][3],wv.w,x3);
  }
  #pragma unroll
  for (int q=0;q<4;q++){
    #pragma unroll
    for (int oo=0;oo<4;oo++){
      float4* xo = (float4*)(x1 + (size_t)(b*64 + o0+oo)*HW + px0);
      float4 old = xo[pg*4 + q];
      old.x += a[oo][q].x; old.y += a[oo][q].y; old.z += a[oo][q].z; old.w += a[oo][q].w;
      xo[pg*4 + q] = old;
    }
  }
}

// ---------------- final scale/shift params (co from partials) ---------------
__global__ void k_mkfinal(const float* __restrict__ fsw, const float* __restrict__ fsb,
                          const float* __restrict__ fhw, const float* __restrict__ fhb,
                          float* __restrict__ ws){
  __shared__ float coL[64];
  const float* part = ws + GX_OFF;
  int tid = threadIdx.x;
  if (tid < 64){
    float s = 0.f;
    for (int bx=0;bx<30;bx++) s += part[bx*64 + tid];
    coL[tid] = s * (1.f/3840.f);
  }
  __syncthreads();
  if (tid < 4){
    int b = tid>>1, o = tid&1;
    const float* co = coL + b*32;
    float s = fsb[o], h = fhb[o];
    for (int k=0;k<32;k++){ s += co[k]*fsw[o*32+k]; h += co[k]*fhw[o*32+k]; }
    ws[FP_OFF + tid] = 1.f + s;
    ws[FP_OFF + 4 + tid] = h;
  }
}

// ---------------- final 1x1 conv + FiLM, bf16 planes ------------------------
__global__ __launch_bounds__(256) void k_final_bf(const float* __restrict__ fw,
                                                  const float* __restrict__ fb,
                                                  const float* __restrict__ ws,
                                                  const unsigned short* __restrict__ xbf,
                                                  float* __restrict__ out){
  __shared__ float w[128];
  __shared__ float pr[8];
  __shared__ float bb[2];
  const int tid = threadIdx.x, blk = blockIdx.x;
  const int b = blk / 960;
  const int px = (blk % 960)*256 + tid;
  if (tid < 128) w[tid] = fw[tid];
  if (tid < 8)   pr[tid] = ws[FP_OFF + tid];
  if (tid < 2)   bb[tid] = fb[tid];
  __syncthreads();
  float a0 = bb[0], a1 = bb[1];
  #pragma unroll
  for (int p=0;p<4;p++){
    const unsigned short* row = xbf + ((size_t)(p*2+b)*HW + px)*16;
    #pragma unroll
    for (int hh=0;hh<2;hh++){
      union { uint4 v; unsigned short us[8]; } u;
      u.v = *(const uint4*)(row + hh*8);
      #pragma unroll
      for (int j=0;j<8;j++){
        int c = p*16 + hh*8 + j;
        float f = bf2f(u.us[j]);
        a0 += w[c]*f; a1 += w[64+c]*f;
      }
    }
  }
  out[((size_t)b*2+0)*HW + px] = a0*pr[b*2+0] + pr[4 + b*2+0];
  out[((size_t)b*2+1)*HW + px] = a1*pr[b*2+1] + pr[4 + b*2+1];
}

// ---------------- final 1x1 conv + FiLM, fp32 planar (fallback) -------------
__global__ __launch_bounds__(256) void k_final(const float* __restrict__ fw,
                                               const float* __restrict__ fb,
                                               const float* __restrict__ ws,
                                               float* __restrict__ out){
  __shared__ float w[128];
  __shared__ float pr[8];
  __shared__ float bb[2];
  const int tid = threadIdx.x, blk = blockIdx.x;
  const int b = blk / 960;
  const int px = (blk % 960)*256 + tid;
  if (tid < 128) w[tid] = fw[tid];
  if (tid < 8)   pr[tid] = ws[FP_OFF + tid];
  if (tid < 2)   bb[tid] = fb[tid];
  __syncthreads();
  const float* xp = ws + X1_OFF + (size_t)b*64*HW + px;
  float a0 = bb[0], a1 = bb[1];
  #pragma unroll
  for (int c=0;c<64;c++){
    float xv = xp[(size_t)c*HW];
    a0 += w[c]*xv; a1 += w[64+c]*xv;
  }
  out[((size_t)b*2+0)*HW + px] = a0*pr[b*2+0] + pr[4 + b*2+0];
  out[((size_t)b*2+1)*HW + px] = a1*pr[b*2+1] + pr[4 + b*2+1];
}

extern "C" void kernel_launch(void* const* d_in, const int* in_sizes, int n_in,
                              void* d_out, int out_size, void* d_ws, size_t ws_size,
                              hipStream_t stream) {
  const float* x            = (const float*)d_in[0];
  const float* cond         = (const float*)d_in[1];
  const float* rep_w1       = (const float*)d_in[2];
  const float* rep_w2       = (const float*)d_in[3];
  const float* lstm_fw_w    = (const float*)d_in[4];
  const float* lstm_bw_w    = (const float*)d_in[5];
  const float* lstm_conv_w  = (const float*)d_in[6];
  const float* lstm_conv_b  = (const float*)d_in[7];
  const float* conv_first_w = (const float*)d_in[8];
  const float* conv_first_b = (const float*)d_in[9];
  const float* bc1_w  = (const float*)d_in[10];
  const float* bc1_b  = (const float*)d_in[11];
  const float* bc2_w  = (const float*)d_in[12];
  const float* bc2_b  = (const float*)d_in[13];
  const float* bc3_w  = (const float*)d_in[14];
  const float* bc3_b  = (const float*)d_in[15];
  const float* bscale_w = (const float*)d_in[16];
  const float* bscale_b = (const float*)d_in[17];
  const float* bshift_w = (const float*)d_in[18];
  const float* bshift_b = (const float*)d_in[19];
  const float* bshare1_w = (const float*)d_in[20];
  const float* bshare1_b = (const float*)d_in[21];
  const float* bdyn1_w   = (const float*)d_in[22];
  const float* bshare2_w = (const float*)d_in[23];
  const float* bshare2_b = (const float*)d_in[24];
  const float* bdyn2_w   = (const float*)d_in[25];
  const float* fc1_w = (const float*)d_in[26];
  const float* fc1_b = (const float*)d_in[27];
  const float* fc2_w = (const float*)d_in[28];
  const float* fc2_b = (const float*)d_in[29];
  const float* fc3_w = (const float*)d_in[30];
  const float* fc3_b = (const float*)d_in[31];
  const float* fconv_w  = (const float*)d_in[32];
  const float* fconv_b  = (const float*)d_in[33];
  const float* fscale_w = (const float*)d_in[34];
  const float* fscale_b = (const float*)d_in[35];
  const float* fshift_w = (const float*)d_in[36];
  const float* fshift_b = (const float*)d_in[37];

  float* ws = (float*)d_ws;
  const bool use_mfma = (ws_size >= REQ_BYTES);
  unsigned short* xbf = use_mfma ? (unsigned short*)((char*)d_ws + X1BF_BYTES_OFF) : (unsigned short*)0;
  unsigned short* wbf = (unsigned short*)((char*)d_ws + WBF_BYTES_OFF);
  unsigned short* w1oc = (unsigned short*)((char*)d_ws + C1_OFF*4UL);
  unsigned short* w2oc = w1oc + 8192;
  float* copart = ws + GX_OFF;

  k_rep1<<<32, 256, 0, stream>>>(cond, rep_w1, ws);
  k_rep2<<<16, 256, 0, stream>>>(rep_w2, ws);
  k_gx<<<128, 256, 0, stream>>>(lstm_fw_w, lstm_bw_w, ws);
  k_lstm<<<dim3(8,2), 256, 0, stream>>>(lstm_fw_w, lstm_bw_w, ws);
  k_ow<<<96, 256, 0, stream>>>(lstm_conv_w, lstm_conv_b, ws);
  if (use_mfma)
    k_wbf<<<1568, 256, 0, stream>>>(bc1_w, fc1_w, wbf);
  k_convfirst<<<1920, 256, 0, stream>>>(x, conv_first_w, conv_first_b,
                                        use_mfma ? (float*)0 : (ws + X1_OFF), xbf);

  for (int j = 0; j < 3; j++){
    if (use_mfma){
      k_conv7_mfma<<<dim3(10,24,2), 256, 0, stream>>>(xbf, wbf + (size_t)j*100352, bc1_b + j*32, ws + C1_OFF);
    } else {
      k_conv7<<<dim3(20,12,2), 256, 0, stream>>>(ws + X1_OFF, bc1_w + (size_t)j*32*64*49, bc1_b + j*32, ws + C1_OFF);
    }
    k_conv3_fast<<<dim3(119,4,2), 256, 0, stream>>>(ws + C1_OFF, bc2_w + (size_t)j*32*32*9, bc2_b + j*32, ws + C2_OFF, 190, 318, 95, 159, (float*)0);
    k_conv3_fast<<<dim3(30,4,2), 256, 0, stream>>>(ws + C2_OFF, bc3_w + (size_t)j*32*32*9, bc3_b + j*32, ws + C3_OFF, 95, 159, 48, 80, copart);
    k_mkparams<<<17, 256, 0, stream>>>(bscale_w + j*2048, bscale_b + j*64,
                                      bshift_w + j*2048, bshift_b + j*64,
                                      bdyn1_w + j*2048, bshare1_w + j*2048, bshare1_b + j*32,
                                      bdyn2_w + j*2048, bshare2_w + j*2048, bshare2_b + j*32,
                                      2*j, ws, w1oc, w2oc);
    if (use_mfma)
      k_pointwise_mfma<<<1920, 256, 0, stream>>>(ws, w1oc, w2oc, xbf);
    else
      k_pointwise<<<3840, 128, 0, stream>>>(ws);
  }

  if (use_mfma){
    k_conv7_mfma<<<dim3(10,24,2), 256, 0, stream>>>(xbf, wbf + (size_t)3*100352, fc1_b, ws + C1_OFF);
  } else {
    k_conv7<<<dim3(20,12,2), 256, 0, stream>>>(ws + X1_OFF, fc1_w, fc1_b, ws + C1_OFF);
  }
  k_conv3_fast<<<dim3(119,4,2), 256, 0, stream>>>(ws + C1_OFF, fc2_w, fc2_b, ws + C2_OFF, 190, 318, 95, 159, (float*)0);
  k_conv3_fast<<<dim3(30,4,2), 256, 0, stream>>>(ws + C2_OFF, fc3_w, fc3_b, ws + C3_OFF, 95, 159, 48, 80, copart);
  k_mkfinal<<<1, 64, 0, stream>>>(fscale_w, fscale_b, fshift_w, fshift_b, ws);
  if (use_mfma)
    k_final_bf<<<1920, 256, 0, stream>>>(fconv_w, fconv_b, ws, xbf, (float*)d_out);
  else
    k_final<<<1920, 256, 0, stream>>>(fconv_w, fconv_b, ws, (float*)d_out);
}

// Round 15
// 686.467 us; speedup vs baseline: 1.0515x; 1.0515x over previous
//
#include <hip/hip_runtime.h>
#include <math.h>

#define HW 245760          // 384*640
#define H_IN 384
#define W_IN 640

// ---- workspace layout (float offsets) ----
#define X1_OFF   0UL
#define C1_OFF   31457280UL
#define C2_OFF   35324160UL
#define C3_OFF   36290880UL
#define T1_OFF   36536640UL
#define REP_OFF  36536768UL
#define GX_OFF   36540864UL
#define WSF_OFF  36573632UL
#define WSB_OFF  36598208UL
#define OW_OFF   36622784UL
#define CO_OFF   36647360UL
#define PAR_OFF  36647424UL
#define FP_OFF   36664192UL
#define P_W1T 0
#define P_W2T 8192
#define P_B1  16384
#define P_B2  16448
#define P_SC  16512
#define P_SH  16640

#define X1BF_BYTES_OFF 146656800UL
#define X1BF_BYTES     62914560UL
#define WBF_BYTES_OFF  (X1BF_BYTES_OFF + X1BF_BYTES)
#define WBF_BYTES      802816UL
#define REQ_BYTES      (WBF_BYTES_OFF + WBF_BYTES)

typedef short short8 __attribute__((ext_vector_type(8)));
typedef unsigned short ushort8_t __attribute__((ext_vector_type(8)));
typedef float f32x16 __attribute__((ext_vector_type(16)));

__device__ __forceinline__ float sigf(float x){ return 1.f/(1.f+expf(-x)); }

__device__ __forceinline__ unsigned short f2bf(float f){
  union { float f; unsigned u; } x; x.f = f;
  unsigned r = x.u + 0x7fffu + ((x.u >> 16) & 1u);   // RNE
  return (unsigned short)(r >> 16);
}
__device__ __forceinline__ float bf2f(unsigned short u){
  union { unsigned u; float f; } x; x.u = ((unsigned)u) << 16; return x.f;
}

// ---------------- rep stage 1 ----------------------------------------------
__global__ __launch_bounds__(256) void k_rep1(const float* __restrict__ cond,
                                              const float* __restrict__ w1,
                                              float* __restrict__ ws){
  const int gid = blockIdx.x*256 + threadIdx.x;
  const int o = gid >> 6;
  const int lane = gid & 63;
  const int r = o >> 6, oc = o & 63;
  const float4* c4 = (const float4*)(cond + r*7680);
  const float4* w4 = (const float4*)(w1 + oc*7680);
  float s = 0.f;
  #pragma unroll 6
  for (int i = lane; i < 1920; i += 64){
    float4 a = c4[i], b = w4[i];
    s += a.x*b.x + a.y*b.y + a.z*b.z + a.w*b.w;
  }
  #pragma unroll
  for (int off = 32; off; off >>= 1) s += __shfl_xor(s, off, 64);
  if (lane == 0) ws[T1_OFF + o] = s > 0.f ? s : 0.1f*s;
}

// ---------------- rep stage 2 -----------------------------------------------
__global__ __launch_bounds__(256) void k_rep2(const float* __restrict__ w2,
                                              float* __restrict__ ws){
  int gid = blockIdx.x*256 + threadIdx.x;
  int r = gid >> 11, j = gid & 2047;
  const float* t1 = ws + T1_OFF + r*64;
  const float* wr = w2 + j*64;
  float s = 0.f;
  #pragma unroll
  for (int k=0;k<64;k++) s += t1[k]*wr[k];
  ws[REP_OFF + gid] = s;
}

// ---------------- gx --------------------------------------------------------
__global__ __launch_bounds__(256) void k_gx(const float* __restrict__ wfw,
                                            const float* __restrict__ wbw,
                                            float* __restrict__ ws){
  int gid = blockIdx.x*256 + threadIdx.x;
  int dir = gid >> 14; int rem = gid & 16383;
  int r = rem >> 8; int m = rem & 255;
  const float* w = (dir ? wbw : wfw) + m*128;
  const float* rp = ws + REP_OFF + r*64;
  float s = 0.f;
  #pragma unroll
  for (int k=0;k<64;k++) s += rp[k]*w[k];
  ws[GX_OFF + gid] = s;
}

// ---------------- LSTM ------------------------------------------------------
__global__ __launch_bounds__(256) void k_lstm(const float* __restrict__ wfw,
                                              const float* __restrict__ wbw,
                                              float* __restrict__ ws){
  const int rg = blockIdx.x, dir = blockIdx.y;
  const int tid = threadIdx.x;
  const int gi = tid >> 6, col = tid & 63;
  const float* w = dir ? wbw : wfw;
  const float* gx = ws + GX_OFF + (size_t)dir*16384;
  float* outp = ws + (dir ? WSB_OFF : WSF_OFF);
  float wr[64];
  const float4* wrow = (const float4*)(w + (gi*64+col)*128 + 64);
  #pragma unroll
  for (int k4=0;k4<16;k4++){
    float4 t = wrow[k4];
    wr[k4*4+0]=t.x; wr[k4*4+1]=t.y; wr[k4*4+2]=t.z; wr[k4*4+3]=t.w;
  }
  __shared__ __align__(16) float hl[512];
  __shared__ float gl[2048];
  hl[tid] = 0.f; hl[tid+256] = 0.f;
  float cs0 = 0.f, cs1 = 0.f;
  __syncthreads();
  for (int t=0;t<6;t++){
    float acc[8];
    #pragma unroll
    for (int r=0;r<8;r++) acc[r] = gx[(rg*8+r)*256 + gi*64 + col];
    #pragma unroll
    for (int r=0;r<8;r++){
      #pragma unroll
      for (int k4=0;k4<16;k4++){
        float4 h4 = *(const float4*)&hl[r*64 + k4*4];
        acc[r] += h4.x*wr[k4*4] + h4.y*wr[k4*4+1] + h4.z*wr[k4*4+2] + h4.w*wr[k4*4+3];
      }
    }
    #pragma unroll
    for (int r=0;r<8;r++) gl[r*256 + gi*64 + col] = acc[r];
    __syncthreads();
    {
      int r = tid >> 6, cc = tid & 63;
      float vi = gl[r*256+cc], vf = gl[r*256+64+cc], vo = gl[r*256+128+cc], vg = gl[r*256+192+cc];
      cs0 = sigf(vf)*cs0 + sigf(vi)*tanhf(vg);
      float h = sigf(vo)*tanhf(cs0);
      hl[r*64+cc] = h;
      outp[t*4096 + (rg*8+r)*64 + cc] = h;
    }
    {
      int cid = tid + 256; int r = cid >> 6, cc = cid & 63;
      float vi = gl[r*256+cc], vf = gl[r*256+64+cc], vo = gl[r*256+128+cc], vg = gl[r*256+192+cc];
      cs1 = sigf(vf)*cs1 + sigf(vi)*tanhf(vg);
      float h = sigf(vo)*tanhf(cs1);
      hl[r*64+cc] = h;
      outp[t*4096 + (rg*8+r)*64 + cc] = h;
    }
    __syncthreads();
  }
}

// ---------------- ow --------------------------------------------------------
__global__ __launch_bounds__(256) void k_ow(const float* __restrict__ lcw,
                                            const float* __restrict__ lcb,
                                            float* __restrict__ ws){
  int gid = blockIdx.x*256 + threadIdx.x;
  int t = gid >> 12; int rem = gid & 4095;
  int r = rem >> 6; int cc = rem & 63;
  const float* wf = lcw + t*8192 + cc*128;
  const float* xf = ws + WSF_OFF + t*4096 + r*64;
  const float* xb = ws + WSB_OFF + (size_t)(5-t)*4096 + r*64;
  float s = lcb[t*64+cc];
  #pragma unroll
  for (int k=0;k<64;k++) s += xf[k]*wf[k];
  #pragma unroll
  for (int k=0;k<64;k++) s += xb[k]*wf[64+k];
  ws[OW_OFF + gid] = s;
}

// ---------------- x1 = conv_first (1x1, 3->64) + bias -----------------------
__global__ __launch_bounds__(256) void k_convfirst(const float* __restrict__ x,
                                                   const float* __restrict__ cw,
                                                   const float* __restrict__ cb,
                                                   float* __restrict__ x1planar,
                                                   unsigned short* __restrict__ xbf){
  __shared__ float wsm[192];
  __shared__ float bsm[64];
  const int tid = threadIdx.x, blk = blockIdx.x;
  const int b = blk / 960;
  const int px = (blk % 960)*256 + tid;
  if (tid < 192) wsm[tid] = cw[tid];
  if (tid < 64)  bsm[tid] = cb[tid];
  __syncthreads();
  float x0 = x[(size_t)(b*3+0)*HW + px];
  float x1v = x[(size_t)(b*3+1)*HW + px];
  float x2 = x[(size_t)(b*3+2)*HW + px];
  float* o = x1planar ? (x1planar + (size_t)b*64*HW + px) : (float*)0;
  #pragma unroll
  for (int i=0;i<8;i++){
    ushort8_t u;
    #pragma unroll
    for (int j=0;j<8;j++){
      int oc = i*8+j;
      float v = bsm[oc] + wsm[oc*3]*x0 + wsm[oc*3+1]*x1v + wsm[oc*3+2]*x2;
      if (x1planar) o[(size_t)oc*HW] = v;
      u[j] = f2bf(v);
    }
    if (xbf)
      *(ushort8_t*)(xbf + (((size_t)(i>>1)*2 + b)*HW + px)*16 + (i&1)*8) = u;
  }
}

// ---------------- weight repack ---------------------------------------------
__global__ __launch_bounds__(256) void k_wbf(const float* __restrict__ bc1w,
                                             const float* __restrict__ fc1w,
                                             unsigned short* __restrict__ wbf){
  int e = blockIdx.x*256 + threadIdx.x;
  int s = e / 100352; int r = e - s*100352;
  int tap = r >> 11; int rem = r & 2047; int oc = rem >> 6; int ic = rem & 63;
  const float* src = (s < 3) ? (bc1w + (size_t)s*100352) : fc1w;
  wbf[e] = f2bf(src[((size_t)oc*64 + ic)*49 + tap]);
}

// ---------------- MFMA 7x7 s2 conv (v5, best measured: 59.2 us) -------------
// 512 thr = 8 waves x 2 output rows. kw-outer: 9 A-frags (static regs) + 7 B
// reads feed 14 MFMAs (1.14 LDS reads/MFMA).
__global__ __launch_bounds__(512, 2) void k_conv7_mfma(
    const unsigned short* __restrict__ xbf,   // [4][2][HW][16] bf16 planes
    const unsigned short* __restrict__ wbf,   // [49][32][64] one set
    const float* __restrict__ bias,
    float* __restrict__ out)                  // [b][32][190][318]
{
  __shared__ __align__(16) unsigned short inS[37*2*36*16];  // 85248 B
  __shared__ __align__(16) unsigned short wS[49*32*16];     // 50176 B
  const int tid = threadIdx.x;
  const int wv = tid >> 6, l = tid & 63;
  const int mrow = l & 31, khalf = l >> 5;
  const int wo0 = blockIdx.x * 32, ho0 = blockIdx.y * 16;
  const int b = blockIdx.z;
  const int r0 = 2*ho0 - 1;

  f32x16 acc0, acc1;
  #pragma unroll
  for (int i=0;i<16;i++){ acc0[i]=0.f; acc1[i]=0.f; }

  for (int kc = 0; kc < 4; ++kc){
    const unsigned short* xplane = xbf + ((size_t)(kc*2 + b))*HW*16;
    __syncthreads();
    for (int idx = tid; idx < 37*72*2; idx += 512){
      int half = idx & 1; int e = idx >> 1;
      int row = e / 72; int rem = e - row*72;
      int p = (rem >= 36) ? 1 : 0;
      int qi = rem - 36*p;
      int r = r0 + row;
      int col = 2*(qi + wo0 - 1) + p;
      uint4 v = make_uint4(0u,0u,0u,0u);
      if ((unsigned)r < 384u && (unsigned)col < 640u)
        v = *(const uint4*)(xplane + ((size_t)r*640 + col)*16 + half*8);
      *(uint4*)(inS + ((size_t)e*16 + half*8)) = v;
    }
    for (int idx = tid; idx < 49*32*2; idx += 512){
      int half = idx & 1; int e = idx >> 1;    // e = tap*32+oc
      uint4 v = *(const uint4*)(wbf + ((size_t)e*64 + kc*16 + half*8));
      *(uint4*)(wS + ((size_t)e*16 + half*8)) = v;
    }
    __syncthreads();

    #pragma unroll
    for (int kw = 0; kw < 7; ++kw){
      const int p = (kw+1)&1;
      const int qoff = (kw - 1 - p)/2 + 1;
      const int abase = ((4*wv)*2 + p)*36 + qoff + mrow;
      short8 A_[9];
      #define LDA(rr) (*(const short8*)(inS + ((size_t)(abase + (rr)*72))*16 + khalf*8))
      #define LDB(KH) (*(const short8*)(wS + ((((KH)*7+kw)*32 + mrow)*16 + khalf*8)))
      #define MF(AV,BV,AC) AC = __builtin_amdgcn_mfma_f32_32x32x16_bf16(AV, BV, AC, 0, 0, 0)
      A_[0]=LDA(0); A_[1]=LDA(1); A_[2]=LDA(2); A_[3]=LDA(3); A_[4]=LDA(4);
      A_[5]=LDA(5); A_[6]=LDA(6); A_[7]=LDA(7); A_[8]=LDA(8);
      #pragma unroll
      for (int kh = 0; kh < 7; ++kh){
        short8 Bq = LDB(kh);
        MF(A_[kh],   Bq, acc0);
        MF(A_[kh+2], Bq, acc1);
      }
      #undef LDA
      #undef LDB
      #undef MF
    }
  }

  const float bv = bias[mrow];
  #pragma unroll
  for (int mt = 0; mt < 2; ++mt){
    int ho = ho0 + 2*wv + mt;
    if (ho >= 190) continue;
    f32x16 av = mt ? acc1 : acc0;
    float* orow = out + (((size_t)b*32 + mrow)*190 + ho)*318;
    #pragma unroll
    for (int r = 0; r < 16; ++r){
      int m = (r&3) + 8*(r>>2) + 4*khalf;
      int wo = wo0 + m;
      if (wo < 318) orow[wo] = fmaxf(av[r] + bv, 0.f);
    }
  }
}

// ---------------- fp32 fallback 7x7 conv ------------------------------------
__global__ __launch_bounds__(256) void k_conv7(const float* __restrict__ in,
                                               const float* __restrict__ w,
                                               const float* __restrict__ bias,
                                               float* __restrict__ out){
  __shared__ float patch[37*37];
  __shared__ __align__(16) float wl[49*32];
  const int tid = threadIdx.x;
  const int og = tid >> 5, s = tid & 31;
  const int sy = s >> 1, sx0 = (s & 1)*8;
  const int bx = blockIdx.x, by = blockIdx.y, b = blockIdx.z;
  const int ir0 = by*32 - 1, ic0 = bx*32 - 1;
  float acc[4][8];
  #pragma unroll
  for (int i=0;i<4;i++)
    #pragma unroll
    for (int k=0;k<8;k++) acc[i][k]=0.f;
  for (int c=0;c<64;c++){
    const float* src = in + (size_t)(b*64+c)*HW;
    for (int idx=tid; idx<1369; idx+=256){
      int r = idx/37; int cc = idx - r*37;
      int ir = ir0 + r, ic = ic0 + cc;
      float v = 0.f;
      if ((unsigned)ir < H_IN && (unsigned)ic < W_IN) v = src[ir*W_IN + ic];
      patch[idx] = v;
    }
    for (int idx=tid; idx<1568; idx+=256)
      wl[idx] = w[((size_t)(idx&31)*64 + c)*49 + (idx>>5)];
    __syncthreads();
    #pragma unroll
    for (int kh=0;kh<7;kh++){
      const float* prow = &patch[(2*sy+kh)*37 + 2*sx0];
      #pragma unroll
      for (int kw=0;kw<7;kw++){
        float4 wv = *(const float4*)&wl[(kh*7+kw)*32 + og*4];
        #pragma unroll
        for (int i=0;i<8;i++){
          float xv = prow[2*i + kw];
          acc[0][i] += wv.x*xv; acc[1][i] += wv.y*xv;
          acc[2][i] += wv.z*xv; acc[3][i] += wv.w*xv;
        }
      }
    }
    __syncthreads();
  }
  const int ho = by*16 + sy;
  if (ho < 190){
    #pragma unroll
    for (int oo=0;oo<4;oo++){
      int o = og*4+oo; float bb = bias[o];
      float* orow = out + ((size_t)(b*32+o)*190 + ho)*318 + bx*16 + sx0;
      #pragma unroll
      for (int i=0;i<8;i++){
        int wo = bx*16 + sx0 + i;
        if (wo < 318) orow[i] = fmaxf(acc[oo][i] + bb, 0.f);
      }
    }
  }
}

// ---------------- 3x3 s2 p1 conv + optional fused spatial-sum ---------------
__global__ __launch_bounds__(256) void k_conv3_fast(const float* __restrict__ in,
                                                    const float* __restrict__ w,
                                                    const float* __restrict__ bias,
                                                    float* __restrict__ out,
                                                    int Hi, int Wi, int Ho, int Wo,
                                                    float* __restrict__ co_partial){
  __shared__ __align__(16) float wl[32*9*8];   // [ic][k][8oc]
  __shared__ float wsum[4][4];
  const int tid = threadIdx.x;
  const int b = blockIdx.z;
  const int oc0 = blockIdx.y * 8;
  for (int idx = tid; idx < 2304; idx += 256){
    int ol = idx & 7; int rest = idx >> 3;
    int ic = rest / 9, k = rest - ic*9;
    wl[idx] = w[((size_t)(oc0+ol)*32 + ic)*9 + k];
  }
  __syncthreads();
  const int pxl = tid & 127, ocg = tid >> 7;
  const int HoWo = Ho*Wo;
  const int opx = blockIdx.x*128 + pxl;
  float acc0=0.f, acc1=0.f, acc2=0.f, acc3=0.f;
  if (opx < HoWo){
    const int ho = opx / Wo, wo = opx - ho*Wo;
    const int ir0 = 2*ho - 1, ic0 = 2*wo - 1;
    const float* inb = in + (size_t)b*32*Hi*Wi;
    for (int c = 0; c < 32; ++c){
      const float* src = inb + (size_t)c*Hi*Wi;
      float xv[9];
      #pragma unroll
      for (int kh=0;kh<3;kh++){
        int ir = ir0 + kh;
        bool rok = (unsigned)ir < (unsigned)Hi;
        #pragma unroll
        for (int kw=0;kw<3;kw++){
          int icc = ic0 + kw;
          xv[kh*3+kw] = (rok && (unsigned)icc < (unsigned)Wi) ? src[ir*Wi + icc] : 0.f;
        }
      }
      const float* wc = &wl[c*72 + ocg*4];
      #pragma unroll
      for (int k=0;k<9;k++){
        float4 wa = *(const float4*)(wc + k*8);
        float x = xv[k];
        acc0 += wa.x*x; acc1 += wa.y*x; acc2 += wa.z*x; acc3 += wa.w*x;
      }
    }
    acc0 = fmaxf(acc0 + bias[oc0+ocg*4+0], 0.f);
    acc1 = fmaxf(acc1 + bias[oc0+ocg*4+1], 0.f);
    acc2 = fmaxf(acc2 + bias[oc0+ocg*4+2], 0.f);
    acc3 = fmaxf(acc3 + bias[oc0+ocg*4+3], 0.f);
    if (!co_partial){
      float* ob = out + ((size_t)(b*32 + oc0 + ocg*4))*HoWo + opx;
      ob[0] = acc0;
      ob[(size_t)HoWo] = acc1;
      ob[(size_t)2*HoWo] = acc2;
      ob[(size_t)3*HoWo] = acc3;
    }
  }
  if (co_partial){
    float r0=acc0, r1=acc1, r2=acc2, r3=acc3;
    #pragma unroll
    for (int off=32; off; off>>=1){
      r0 += __shfl_xor(r0, off, 64);
      r1 += __shfl_xor(r1, off, 64);
      r2 += __shfl_xor(r2, off, 64);
      r3 += __shfl_xor(r3, off, 64);
    }
    int wvid = tid >> 6;
    if ((tid & 63) == 0){
      wsum[wvid][0]=r0; wsum[wvid][1]=r1; wsum[wvid][2]=r2; wsum[wvid][3]=r3;
    }
    __syncthreads();
    if (tid < 8){
      int i = tid & 3; int pair = tid >> 2;
      float v = wsum[pair*2][i] + wsum[pair*2+1][i];
      co_partial[(size_t)blockIdx.x*64 + b*32 + oc0 + pair*4 + i] = v;
    }
  }
}

// ---------------- per-block params (parallelized) ---------------------------
__global__ __launch_bounds__(256) void k_mkparams(const float* __restrict__ bsw, const float* __restrict__ bsb,
                                                  const float* __restrict__ bhw, const float* __restrict__ bhb,
                                                  const float* __restrict__ dyn1, const float* __restrict__ sh1w, const float* __restrict__ sh1b,
                                                  const float* __restrict__ dyn2, const float* __restrict__ sh2w, const float* __restrict__ sh2b,
                                                  int j2, float* __restrict__ ws,
                                                  unsigned short* __restrict__ w1oc,
                                                  unsigned short* __restrict__ w2oc){
  const int bid = blockIdx.x;
  const int tid = threadIdx.x;
  float* P = ws + PAR_OFF;
  if (bid < 16){
    const float* ow1 = ws + OW_OFF + (size_t)j2*4096;
    const float* ow2 = ws + OW_OFF + (size_t)(j2+1)*4096;
    for (int idx = bid*256 + tid; idx < 8192; idx += 4096){
      int b = idx>>12, rem = idx&4095, c = rem>>6, o = rem&63;
      float v1, v2;
      if (o < 32){
        v1 = dyn1[o*64+c]*ow1[(b*32+o)*64+c];
        v2 = dyn2[o*64+c]*ow2[(b*32+o)*64+c];
      } else {
        v1 = sh1w[(o-32)*64+c];
        v2 = sh2w[(o-32)*64+c];
      }
      P[P_W1T + idx] = v1;
      P[P_W2T + idx] = v2;
      int t = b*4096 + o*64 + c;
      w1oc[t] = f2bf(v1);
      w2oc[t] = f2bf(v2);
    }
  } else {
    __shared__ float coL[64];
    const float* part = ws + GX_OFF;
    if (tid < 64){
      float s = 0.f;
      for (int bx=0;bx<30;bx++) s += part[bx*64 + tid];
      coL[tid] = s * (1.f/3840.f);
    }
    __syncthreads();
    if (tid < 128){
      int b = tid>>6, o = tid&63;
      float s = bsb[o];
      #pragma unroll
      for (int k=0;k<32;k++) s += coL[b*32+k]*bsw[o*32+k];
      P[P_SC + tid] = 1.f + s;
    } else {
      int t2 = tid-128; int b = t2>>6, o = t2&63;
      float s = bhb[o];
      #pragma unroll
      for (int k=0;k<32;k++) s += coL[b*32+k]*bhw[o*32+k];
      P[P_SH + t2] = s;
    }
    if (tid < 64){
      P[P_B1+tid] = (tid<32) ? 0.f : sh1b[tid-32];
      P[P_B2+tid] = (tid<32) ? 0.f : sh2b[tid-32];
    }
  }
}

// ---------------- MFMA fused dynamic block (bf16-resident x1, planes) -------
__global__ __launch_bounds__(256, 4) void k_pointwise_mfma(
    const float* __restrict__ ws,
    const unsigned short* __restrict__ w1oc,
    const unsigned short* __restrict__ w2oc,
    unsigned short* __restrict__ xbf)
{
  __shared__ float scs[64], shs[64], b1s[64], b2s[64];
  __shared__ __align__(16) uint4 outbuf[2048];
  const int tid = threadIdx.x;
  const int blk = blockIdx.x;
  const int b = blk / 960;
  const int px0 = (blk % 960) * 256;
  const float* P = ws + PAR_OFF;
  if (tid < 64){
    scs[tid] = P[P_SC + b*64 + tid];
    shs[tid] = P[P_SH + b*64 + tid];
    b1s[tid] = P[P_B1 + tid];
    b2s[tid] = P[P_B2 + tid];
  }
  __syncthreads();
  const int wv = tid >> 6, l = tid & 63;
  const int lane31 = l & 31, myh = l >> 5;
  const unsigned short* w1g = w1oc + (size_t)b*4096;
  const unsigned short* w2g = w2oc + (size_t)b*4096;

  #pragma unroll
  for (int nt = 0; nt < 2; ++nt){
    const int pxl = wv*64 + nt*32 + lane31;
    const int mypx = px0 + pxl;
    short8 Bsave[4];
    f32x16 a1_0, a1_1;
    #pragma unroll
    for (int i=0;i<16;i++){ a1_0[i]=0.f; a1_1[i]=0.f; }
    #pragma unroll
    for (int kc=0;kc<4;kc++){
      short8 Bx = *(const short8*)(xbf + ((size_t)(kc*2+b)*HW + mypx)*16 + myh*8);
      Bsave[kc] = Bx;
      short8 A0 = *(const short8*)(w1g + (size_t)lane31*64 + kc*16 + myh*8);
      short8 A1 = *(const short8*)(w1g + (size_t)(32+lane31)*64 + kc*16 + myh*8);
      a1_0 = __builtin_amdgcn_mfma_f32_32x32x16_bf16(A0, Bx, a1_0, 0, 0, 0);
      a1_1 = __builtin_amdgcn_mfma_f32_32x32x16_bf16(A1, Bx, a1_1, 0, 0, 0);
    }
    unsigned hp0[8], hp1[8];
    #pragma unroll
    for (int mt=0;mt<2;mt++){
      #pragma unroll
      for (int p=0;p<8;p++){
        unsigned half0=0, half1=0;
        #pragma unroll
        for (int e=0;e<2;e++){
          int reg = 2*p+e;
          int o1 = mt*32 + (reg&3) + 8*(reg>>2) + 4*myh;
          float v = mt ? a1_1[reg] : a1_0[reg];
          float t = (v + b1s[o1]) * scs[o1] + shs[o1];
          t = fmaxf(t, 0.f);
          if (e) half1 = f2bf(t); else half0 = f2bf(t);
        }
        unsigned pk = half0 | (half1<<16);
        if (mt) hp1[p] = pk; else hp0[p] = pk;
      }
    }
    f32x16 a2_0, a2_1;
    #pragma unroll
    for (int i=0;i<16;i++){ a2_0[i]=0.f; a2_1[i]=0.f; }
    #pragma unroll
    for (int kc=0;kc<4;kc++){
      const int base = 4*(kc&1);
      unsigned e0,e1,e2,e3;
      if (kc < 2){ e0=hp0[base+0]; e1=hp0[base+1]; e2=hp0[base+2]; e3=hp0[base+3]; }
      else       { e0=hp1[base+0]; e1=hp1[base+1]; e2=hp1[base+2]; e3=hp1[base+3]; }
      unsigned sA = myh ? e0 : e2;
      unsigned sB = myh ? e1 : e3;
      unsigned rA = __shfl_xor(sA, 32, 64);
      unsigned rB = __shfl_xor(sB, 32, 64);
      union { unsigned u[4]; short8 s; } Bh;
      Bh.u[0] = myh ? rA : e0;
      Bh.u[1] = myh ? rB : e1;
      Bh.u[2] = myh ? e2 : rA;
      Bh.u[3] = myh ? e3 : rB;
      short8 A0 = *(const short8*)(w2g + (size_t)lane31*64 + kc*16 + myh*8);
      short8 A1 = *(const short8*)(w2g + (size_t)(32+lane31)*64 + kc*16 + myh*8);
      a2_0 = __builtin_amdgcn_mfma_f32_32x32x16_bf16(A0, Bh.s, a2_0, 0, 0, 0);
      a2_1 = __builtin_amdgcn_mfma_f32_32x32x16_bf16(A1, Bh.s, a2_1, 0, 0, 0);
    }
    #pragma unroll
    for (int mt2=0;mt2<2;mt2++){
      #pragma unroll
      for (int q=0;q<4;q++){
        float d[4], p[4];
        #pragma unroll
        for (int e=0;e<4;e++){
          int reg = 4*q+e;
          int ch = mt2*32 + e + 8*q + 4*myh;
          d[e] = (mt2 ? a2_1[reg] : a2_0[reg]) + b2s[ch];
        }
        #pragma unroll
        for (int e=0;e<4;e++) p[e] = __shfl_xor(d[e], 32, 64);
        if (myh == (q & 1)){
          float row8[8];
          #pragma unroll
          for (int e=0;e<4;e++){
            row8[e]   = myh ? p[e] : d[e];
            row8[4+e] = myh ? d[e] : p[e];
          }
          union { short8 s; unsigned short us[8]; } oldv;
          oldv.s = Bsave[2*mt2 + (q>>1)];
          unsigned w[4];
          #pragma unroll
          for (int k=0;k<4;k++){
            float n0 = bf2f(oldv.us[2*k+0]) + row8[2*k+0];
            float n1 = bf2f(oldv.us[2*k+1]) + row8[2*k+1];
            w[k] = (unsigned)f2bf(n0) | ((unsigned)f2bf(n1) << 16);
          }
          int slot = mt2*4 + q;
          outbuf[pxl*8 + ((slot + pxl) & 7)] = make_uint4(w[0],w[1],w[2],w[3]);
        }
      }
    }
  }
  __syncthreads();
  uint4* gout = (uint4*)xbf;
  #pragma unroll
  for (int k=0;k<8;k++){
    int idx = tid + k*256;
    int plane = idx >> 9, rem = idx & 511;
    int pxl = rem >> 1, half = rem & 1;
    int slot = plane*2 + half;
    gout[((size_t)(plane*2+b)*HW + px0 + pxl)*2 + half] = outbuf[pxl*8 + ((slot + pxl) & 7)];
  }
}

// ---------------- fallback fused dynamic block (fp32 VALU) ------------------
#define FMA4(A,W,X) { A.x += (W)*(X).x; A.y += (W)*(X).y; A.z += (W)*(X).z; A.w += (W)*(X).w; }
__global__ __launch_bounds__(128) void k_pointwise(float* __restrict__ ws){
  __shared__ __align__(16) float xt[64*128];
  __shared__ __align__(16) float wt[64*64];
  __shared__ float b1s[64], b2s[64], scs[64], shs[64];
  const int tid = threadIdx.x;
  const int blk = blockIdx.x;
  const int b = blk / 1920;
  const int px0 = (blk % 1920) * 128;
  float* x1 = ws + X1_OFF;
  const float* P = ws + PAR_OFF;
  const float4* xg = (const float4*)(x1 + (size_t)b*64*HW + px0);
  float4* xt4 = (float4*)xt;
  float4* wt4 = (float4*)wt;
  for (int idx=tid; idx<2048; idx+=128){
    int c = idx>>5, p4 = idx&31;
    xt4[c*32 + (p4&3)*8 + (p4>>2)] = xg[(size_t)c*(HW/4) + p4];
  }
  const float4* w1g = (const float4*)(P + P_W1T + b*4096);
  for (int idx=tid; idx<1024; idx+=128) wt4[idx] = w1g[idx];
  if (tid < 64){
    b1s[tid]=P[P_B1+tid]; b2s[tid]=P[P_B2+tid];
    scs[tid]=P[P_SC + b*64 + tid]; shs[tid]=P[P_SH + b*64 + tid];
  }
  __syncthreads();
  const int og = tid>>3, pg = tid&7, o0 = og*4;
  float4 a[4][4];
  #pragma unroll
  for (int oo=0;oo<4;oo++){
    float bv = b1s[o0+oo];
    a[oo][0]=a[oo][1]=a[oo][2]=a[oo][3]=make_float4(bv,bv,bv,bv);
  }
  for (int c=0;c<64;c++){
    float4 wv = wt4[c*16 + og];
    float4 x0 = xt4[c*32 + pg];
    float4 x1q = xt4[c*32 + 8 + pg];
    float4 x2 = xt4[c*32 + 16 + pg];
    float4 x3 = xt4[c*32 + 24 + pg];
    FMA4(a[0][0],wv.x,x0); FMA4(a[0][1],wv.x,x1q); FMA4(a[0][2],wv.x,x2); FMA4(a[0][3],wv.x,x3);
    FMA4(a[1][0],wv.y,x0); FMA4(a[1][1],wv.y,x1q); FMA4(a[1][2],wv.y,x2); FMA4(a[1][3],wv.y,x3);
    FMA4(a[2][0],wv.z,x0); FMA4(a[2][1],wv.z,x1q); FMA4(a[2][2],wv.z,x2); FMA4(a[2][3],wv.z,x3);
    FMA4(a[3][0],wv.w,x0); FMA4(a[3][1],wv.w,x1q); FMA4(a[3][2],wv.w,x2); FMA4(a[3][3],wv.w,x3);
  }
  #pragma unroll
  for (int oo=0;oo<4;oo++){
    float sc = scs[o0+oo], sh = shs[o0+oo];
    #pragma unroll
    for (int q=0;q<4;q++){
      a[oo][q].x = fmaxf(a[oo][q].x*sc + sh, 0.f);
      a[oo][q].y = fmaxf(a[oo][q].y*sc + sh, 0.f);
      a[oo][q].z = fmaxf(a[oo][q].z*sc + sh, 0.f);
      a[oo][q].w = fmaxf(a[oo][q].w*sc + sh, 0.f);
    }
  }
  __syncthreads();
  #pragma unroll
  for (int oo=0;oo<4;oo++)
    #pragma unroll
    for (int q=0;q<4;q++)
      xt4[(o0+oo)*32 + q*8 + pg] = a[oo][q];
  const float4* w2g = (const float4*)(P + P_W2T + b*4096);
  for (int idx=tid; idx<1024; idx+=128) wt4[idx] = w2g[idx];
  __syncthreads();
  #pragma unroll
  for (int oo=0;oo<4;oo++){
    float bv = b2s[o0+oo];
    a[oo][0]=a[oo][1]=a[oo][2]=a[oo][3]=make_float4(bv,bv,bv,bv);
  }
  for (int c=0;c<64;c++){
    float4 wv = wt4[c*16 + og];
    float4 x0 = xt4[c*32 + pg];
    float4 x1q = xt4[c*32 + 8 + pg];
    float4 x2 = xt4[c*32 + 16 + pg];
    float4 x3 = xt4[c*32 + 24 + pg];
    FMA4(a[0][0],wv.x,x0); FMA4(a[0][1],wv.x,x1q); FMA4(a[0][2],wv.x,x2); FMA4(a[0][3],wv.x,x3);
    FMA4(a[1][0],wv.y,x0); FMA4(a[1][1],wv.y,x1q); FMA4(a[1][2],wv.y,x2); FMA4(a[1][3],wv.y,x3);
    FMA4(a[2][0],wv.z,x0); FMA4(a[2][1],wv.z,x1q); FMA4(a[2][2],wv.z,x2); FMA4(a[2][3],wv.z,x3);
    FMA4(a[3][0],wv.w,x0); FMA4(a[3][1],wv.w,x1q); FMA4(a[3][2],wv.w,x2); FMA4(a[3][3],wv.w,x3);
  }
  #pragma unroll
  for (int q=0;q<4;q++){
    #pragma unroll
    for (int oo=0;oo<4;oo++){
      float4* xo = (float4*)(x1 + (size_t)(b*64 + o0+oo)*HW + px0);
      float4 old = xo[pg*4 + q];
      old.x += a[oo][q].x; old.y += a[oo][q].y; old.z += a[oo][q].z; old.w += a[oo][q].w;
      xo[pg*4 + q] = old;
    }
  }
}

// ---------------- final scale/shift params (co from partials) ---------------
__global__ void k_mkfinal(const float* __restrict__ fsw, const float* __restrict__ fsb,
                          const float* __restrict__ fhw, const float* __restrict__ fhb,
                          float* __restrict__ ws){
  __shared__ float coL[64];
  const float* part = ws + GX_OFF;
  int tid = threadIdx.x;
  if (tid < 64){
    float s = 0.f;
    for (int bx=0;bx<30;bx++) s += part[bx*64 + tid];
    coL[tid] = s * (1.f/3840.f);
  }
  __syncthreads();
  if (tid < 4){
    int b = tid>>1, o = tid&1;
    const float* co = coL + b*32;
    float s = fsb[o], h = fhb[o];
    for (int k=0;k<32;k++){ s += co[k]*fsw[o*32+k]; h += co[k]*fhw[o*32+k]; }
    ws[FP_OFF + tid] = 1.f + s;
    ws[FP_OFF + 4 + tid] = h;
  }
}

// ---------------- final 1x1 conv + FiLM, bf16 planes ------------------------
__global__ __launch_bounds__(256) void k_final_bf(const float* __restrict__ fw,
                                                  const float* __restrict__ fb,
                                                  const float* __restrict__ ws,
                                                  const unsigned short* __restrict__ xbf,
                                                  float* __restrict__ out){
  __shared__ float w[128];
  __shared__ float pr[8];
  __shared__ float bb[2];
  const int tid = threadIdx.x, blk = blockIdx.x;
  const int b = blk / 960;
  const int px = (blk % 960)*256 + tid;
  if (tid < 128) w[tid] = fw[tid];
  if (tid < 8)   pr[tid] = ws[FP_OFF + tid];
  if (tid < 2)   bb[tid] = fb[tid];
  __syncthreads();
  float a0 = bb[0], a1 = bb[1];
  #pragma unroll
  for (int p=0;p<4;p++){
    const unsigned short* row = xbf + ((size_t)(p*2+b)*HW + px)*16;
    #pragma unroll
    for (int hh=0;hh<2;hh++){
      union { uint4 v; unsigned short us[8]; } u;
      u.v = *(const uint4*)(row + hh*8);
      #pragma unroll
      for (int j=0;j<8;j++){
        int c = p*16 + hh*8 + j;
        float f = bf2f(u.us[j]);
        a0 += w[c]*f; a1 += w[64+c]*f;
      }
    }
  }
  out[((size_t)b*2+0)*HW + px] = a0*pr[b*2+0] + pr[4 + b*2+0];
  out[((size_t)b*2+1)*HW + px] = a1*pr[b*2+1] + pr[4 + b*2+1];
}

// ---------------- final 1x1 conv + FiLM, fp32 planar (fallback) -------------
__global__ __launch_bounds__(256) void k_final(const float* __restrict__ fw,
                                               const float* __restrict__ fb,
                                               const float* __restrict__ ws,
                                               float* __restrict__ out){
  __shared__ float w[128];
  __shared__ float pr[8];
  __shared__ float bb[2];
  const int tid = threadIdx.x, blk = blockIdx.x;
  const int b = blk / 960;
  const int px = (blk % 960)*256 + tid;
  if (tid < 128) w[tid] = fw[tid];
  if (tid < 8)   pr[tid] = ws[FP_OFF + tid];
  if (tid < 2)   bb[tid] = fb[tid];
  __syncthreads();
  const float* xp = ws + X1_OFF + (size_t)b*64*HW + px;
  float a0 = bb[0], a1 = bb[1];
  #pragma unroll
  for (int c=0;c<64;c++){
    float xv = xp[(size_t)c*HW];
    a0 += w[c]*xv; a1 += w[64+c]*xv;
  }
  out[((size_t)b*2+0)*HW + px] = a0*pr[b*2+0] + pr[4 + b*2+0];
  out[((size_t)b*2+1)*HW + px] = a1*pr[b*2+1] + pr[4 + b*2+1];
}

extern "C" void kernel_launch(void* const* d_in, const int* in_sizes, int n_in,
                              void* d_out, int out_size, void* d_ws, size_t ws_size,
                              hipStream_t stream) {
  const float* x            = (const float*)d_in[0];
  const float* cond         = (const float*)d_in[1];
  const float* rep_w1       = (const float*)d_in[2];
  const float* rep_w2       = (const float*)d_in[3];
  const float* lstm_fw_w    = (const float*)d_in[4];
  const float* lstm_bw_w    = (const float*)d_in[5];
  const float* lstm_conv_w  = (const float*)d_in[6];
  const float* lstm_conv_b  = (const float*)d_in[7];
  const float* conv_first_w = (const float*)d_in[8];
  const float* conv_first_b = (const float*)d_in[9];
  const float* bc1_w  = (const float*)d_in[10];
  const float* bc1_b  = (const float*)d_in[11];
  const float* bc2_w  = (const float*)d_in[12];
  const float* bc2_b  = (const float*)d_in[13];
  const float* bc3_w  = (const float*)d_in[14];
  const float* bc3_b  = (const float*)d_in[15];
  const float* bscale_w = (const float*)d_in[16];
  const float* bscale_b = (const float*)d_in[17];
  const float* bshift_w = (const float*)d_in[18];
  const float* bshift_b = (const float*)d_in[19];
  const float* bshare1_w = (const float*)d_in[20];
  const float* bshare1_b = (const float*)d_in[21];
  const float* bdyn1_w   = (const float*)d_in[22];
  const float* bshare2_w = (const float*)d_in[23];
  const float* bshare2_b = (const float*)d_in[24];
  const float* bdyn2_w   = (const float*)d_in[25];
  const float* fc1_w = (const float*)d_in[26];
  const float* fc1_b = (const float*)d_in[27];
  const float* fc2_w = (const float*)d_in[28];
  const float* fc2_b = (const float*)d_in[29];
  const float* fc3_w = (const float*)d_in[30];
  const float* fc3_b = (const float*)d_in[31];
  const float* fconv_w  = (const float*)d_in[32];
  const float* fconv_b  = (const float*)d_in[33];
  const float* fscale_w = (const float*)d_in[34];
  const float* fscale_b = (const float*)d_in[35];
  const float* fshift_w = (const float*)d_in[36];
  const float* fshift_b = (const float*)d_in[37];

  float* ws = (float*)d_ws;
  const bool use_mfma = (ws_size >= REQ_BYTES);
  unsigned short* xbf = use_mfma ? (unsigned short*)((char*)d_ws + X1BF_BYTES_OFF) : (unsigned short*)0;
  unsigned short* wbf = (unsigned short*)((char*)d_ws + WBF_BYTES_OFF);
  unsigned short* w1oc = (unsigned short*)((char*)d_ws + C1_OFF*4UL);
  unsigned short* w2oc = w1oc + 8192;
  float* copart = ws + GX_OFF;

  k_rep1<<<32, 256, 0, stream>>>(cond, rep_w1, ws);
  k_rep2<<<16, 256, 0, stream>>>(rep_w2, ws);
  k_gx<<<128, 256, 0, stream>>>(lstm_fw_w, lstm_bw_w, ws);
  k_lstm<<<dim3(8,2), 256, 0, stream>>>(lstm_fw_w, lstm_bw_w, ws);
  k_ow<<<96, 256, 0, stream>>>(lstm_conv_w, lstm_conv_b, ws);
  if (use_mfma)
    k_wbf<<<1568, 256, 0, stream>>>(bc1_w, fc1_w, wbf);
  k_convfirst<<<1920, 256, 0, stream>>>(x, conv_first_w, conv_first_b,
                                        use_mfma ? (float*)0 : (ws + X1_OFF), xbf);

  for (int j = 0; j < 3; j++){
    if (use_mfma){
      k_conv7_mfma<<<dim3(10,12,2), 512, 0, stream>>>(xbf, wbf + (size_t)j*100352, bc1_b + j*32, ws + C1_OFF);
    } else {
      k_conv7<<<dim3(20,12,2), 256, 0, stream>>>(ws + X1_OFF, bc1_w + (size_t)j*32*64*49, bc1_b + j*32, ws + C1_OFF);
    }
    k_conv3_fast<<<dim3(119,4,2), 256, 0, stream>>>(ws + C1_OFF, bc2_w + (size_t)j*32*32*9, bc2_b + j*32, ws + C2_OFF, 190, 318, 95, 159, (float*)0);
    k_conv3_fast<<<dim3(30,4,2), 256, 0, stream>>>(ws + C2_OFF, bc3_w + (size_t)j*32*32*9, bc3_b + j*32, ws + C3_OFF, 95, 159, 48, 80, copart);
    k_mkparams<<<17, 256, 0, stream>>>(bscale_w + j*2048, bscale_b + j*64,
                                      bshift_w + j*2048, bshift_b + j*64,
                                      bdyn1_w + j*2048, bshare1_w + j*2048, bshare1_b + j*32,
                                      bdyn2_w + j*2048, bshare2_w + j*2048, bshare2_b + j*32,
                                      2*j, ws, w1oc, w2oc);
    if (use_mfma)
      k_pointwise_mfma<<<1920, 256, 0, stream>>>(ws, w1oc, w2oc, xbf);
    else
      k_pointwise<<<3840, 128, 0, stream>>>(ws);
  }

  if (use_mfma){
    k_conv7_mfma<<<dim3(10,12,2), 512, 0, stream>>>(xbf, wbf + (size_t)3*100352, fc1_b, ws + C1_OFF);
  } else {
    k_conv7<<<dim3(20,12,2), 256, 0, stream>>>(ws + X1_OFF, fc1_w, fc1_b, ws + C1_OFF);
  }
  k_conv3_fast<<<dim3(119,4,2), 256, 0, stream>>>(ws + C1_OFF, fc2_w, fc2_b, ws + C2_OFF, 190, 318, 95, 159, (float*)0);
  k_conv3_fast<<<dim3(30,4,2), 256, 0, stream>>>(ws + C2_OFF, fc3_w, fc3_b, ws + C3_OFF, 95, 159, 48, 80, copart);
  k_mkfinal<<<1, 64, 0, stream>>>(fscale_w, fscale_b, fshift_w, fshift_b, ws);
  if (use_mfma)
    k_final_bf<<<1920, 256, 0, stream>>>(fconv_w, fconv_b, ws, xbf, (float*)d_out);
  else
    k_final<<<1920, 256, 0, stream>>>(fconv_w, fconv_b, ws, (float*)d_out);
}